// Round 13
// baseline (228.482 us; speedup 1.0000x reference)
//
#include <hip/hip_runtime.h>
#include <cstdint>
#include <cstddef>

// ---------------------------------------------------------------------------
// DetCenterDense: fused conv3x3(128->64)+ReLU -> 4x conv1x1 heads (20 ch total,
// sigmoid on last 4) over [4,128,512,512] fp32, NCHW. bf16 MFMA implicit GEMM.
// R13 (final): exact revert to R11, the verified session best (227 us).
//   - 256-thr blocks, 12 waves/CU; A double-buffered LDS (swizzled) + 1-deep
//     register prefetch; B single LDS buffer via global_load_lds; 2 barriers
//     per 16-cin half-chunk; counted vmcnt(9) keeps A(h+2) in flight across
//     barriers; XCD-aware block swizzle; no setprio.
//   - ORDER MATTERS: writeA(h+1) MUST precede issueA(h+2) — R[] is a single
//     register buffer; issuing first overwrites it (R12's WAR bug, absmax 9.5).
// Explored and rejected (measured): B-from-global (+28us), 4x64 tile (+33),
// 8-wave blocks (+17), mt=4 acc (spill), feat-transpose prepass (+118),
// setprio (neutral), issueA-before-writeA (WRONG).
// ---------------------------------------------------------------------------

typedef __bf16 bf16x8 __attribute__((ext_vector_type(8)));
typedef float f32x16 __attribute__((ext_vector_type(16)));
typedef float f32x4v __attribute__((ext_vector_type(4)));
typedef float f32x2v __attribute__((ext_vector_type(2)));

#define CHW (512 * 512)

// A-tile LDS swizzle (validated R3-R11): granule 16B at (slot s, octet o):
//   lin = s*32 + o*16 ; byte = lin ^ ((lin>>1)&0x10) ^ ((lin>>2)&0x60)
__device__ __forceinline__ int swz(int s, int o) {
    int lin = (s << 5) | (o << 4);
    return lin ^ ((lin >> 1) & 0x10) ^ ((lin >> 2) & 0x60);
}

// ---------------------------------------------------------------------------
// Prepass: repack w_shared [64][128][3][3] fp32 -> bf16, per-half-chunk
// contiguous: ws3 [hc(8)][tap(9)][hw(2)][och(64)][8 bf16]  (18432 B per hc)
// ---------------------------------------------------------------------------
__global__ void prep_w_kernel(const float* __restrict__ w, __bf16* __restrict__ ws3) {
    int idx = blockIdx.x * 256 + threadIdx.x;
    if (idx >= 64 * 128 * 9) return;
    int tap = idx % 9;
    int cin = (idx / 9) % 128;
    int och = idx / (9 * 128);
    int hc = cin >> 4;
    int hw = (cin >> 3) & 1;
    int j  = cin & 7;
    int dst = (((hc * 9 + tap) * 2 + hw) * 64 + och) * 8 + j;
    ws3[dst] = (__bf16)w[idx];
}

// LDS map (bytes), total 52224 -> 3 blocks/CU (156672 <= 163840):
//   A0 @ 0 [16896]   A1 @ 16896 [16896]   ([4 rows][132 slots x 32B], swz)
//   B  @ 33792 [18432] single buf: [tap 9][hw 2][och 64][8 bf16], linear.
//   After main loop: wc overlays @33792 [4096], bias @37888 [128]; X tile @0.
#define A_OFF(p)  ((p) ? 16896 : 0)
#define B_BASE    33792
#define WC_BASE   33792
#define BIAS_BASE 37888

__global__ __launch_bounds__(256, 3)
void det_main_kernel(const float* __restrict__ feature,
                     const __bf16* __restrict__ ws3,
                     const float* __restrict__ w_cls, const float* __restrict__ b_cls,
                     const float* __restrict__ w_box, const float* __restrict__ b_box,
                     const float* __restrict__ w_dir, const float* __restrict__ b_dir,
                     const float* __restrict__ w_scr, const float* __restrict__ b_scr,
                     float* __restrict__ out) {
    __shared__ __align__(1024) char s_all[52224];

    const int tid  = threadIdx.x;
    const int lane = tid & 63;
    const int wave = tid >> 6;
    const int l31  = lane & 31;
    const int hw   = lane >> 5;
    const int wrow = wave >> 1;
    const int wcb  = (wave & 1) * 64;

    // XCD-aware decode: 4096 blocks -> 8 chunks of 512; vertical neighbors
    // (sharing halo rows) schedule-adjacent within an XCD.
    const int bid = blockIdx.x;
    const int wg  = (bid & 7) * 512 + (bid >> 3);
    const int ck  = wg >> 9;
    const int bz  = ck >> 1;
    const int rem = wg & 511;
    const int h0  = (rem >> 1) * 2;
    const int w0  = ((ck & 1) * 2 + (rem & 1)) * 128;

    // ---- staging roles (R4-validated) ----
    // main: thread covers (cin octet m_hw, slot-quad m_q, row m_row): 8 dwordx4
    const int m_hw  = tid & 1;
    const int m_q   = (tid >> 1) & 31;
    const int m_row = tid >> 6;
    const int m_h   = h0 - 1 + m_row;
    const bool m_ok = (unsigned)m_h < 512u;
    const float* m_base = feature + (size_t)(bz * 128 + m_hw * 8) * CHW
                        + (size_t)(m_ok ? m_h : 0) * 512 + (w0 + 4 * m_q);
    // edge: even lanes of every wave (uniform per-wave instr count): 1 dwordx2
    const bool e_on = (tid & 1) == 0;
    const int e_idx = tid >> 1;
    const int e_ee  = (e_idx >> 6) & 1;
    const int e_row = (e_idx >> 4) & 3;
    const int e_cin = e_idx & 15;
    const int e_h   = h0 - 1 + e_row;
    const int e_w   = e_ee ? (w0 + 128) : (w0 - 2);
    const bool e_ok = ((unsigned)e_h < 512u) && ((unsigned)e_w < 511u);
    const float* e_base = feature + (size_t)(bz * 128 + e_cin) * CHW
                        + (size_t)(e_ok ? e_h : 0) * 512 + (e_ok ? e_w : 0);

    f32x4v R[8];      // 1-deep A prefetch (32 VGPR)
    f32x2v E;

    // issue A-loads for half-chunk hc: ALWAYS 9 vmem instrs per wave.
    auto issueA = [&](int hc) {
        const float* p = m_base + (size_t)(hc * 16) * CHW;
        #pragma unroll
        for (int j = 0; j < 8; ++j) R[j] = *(const f32x4v*)(p + (size_t)j * CHW);
        if (e_on) E = *(const f32x2v*)(e_base + (size_t)(hc * 16) * CHW);
    };

    // convert + ds_write into A-buf[hc&1]; zero OOB here (no vmem).
    auto writeA = [&](int hc) {
        char* ab = s_all + A_OFF(hc & 1);
        #pragma unroll
        for (int k = 0; k < 4; ++k) {
            bf16x8 g;
            #pragma unroll
            for (int j = 0; j < 8; ++j) g[j] = (__bf16)(m_ok ? R[j][k] : 0.f);
            *(bf16x8*)(ab + m_row * 4224 + swz(2 + 4 * m_q + k, m_hw)) = g;
        }
        if (e_on) {
            char* b2 = ab + e_row * 4224 + (e_cin & 7) * 2;
            int s0 = e_ee ? 130 : 0;
            *(__bf16*)(b2 + swz(s0,     e_cin >> 3)) = (__bf16)(e_ok ? E[0] : 0.f);
            *(__bf16*)(b2 + swz(s0 + 1, e_cin >> 3)) = (__bf16)(e_ok ? E[1] : 0.f);
        }
    };

    // async global->LDS of hc's weights into single B buffer (1152 x 16B).
    auto issueB = [&](int hc) {
        char* bb = s_all + B_BASE;
        const char* src = (const char*)ws3 + hc * 18432;
        #pragma unroll
        for (int i = 0; i < 4; ++i) {
            int g0 = i * 256 + wave * 64;
            __builtin_amdgcn_global_load_lds(
                (const __attribute__((address_space(1))) void*)(src + (size_t)(g0 + lane) * 16),
                (__attribute__((address_space(3))) void*)(bb + g0 * 16), 16, 0, 0);
        }
        if (wave < 2) {
            int g0 = 1024 + wave * 64;
            __builtin_amdgcn_global_load_lds(
                (const __attribute__((address_space(1))) void*)(src + (size_t)(g0 + lane) * 16),
                (__attribute__((address_space(3))) void*)(bb + g0 * 16), 16, 0, 0);
        }
    };

    f32x16 zero16;
    #pragma unroll
    for (int e = 0; e < 16; ++e) zero16[e] = 0.f;
    f32x16 acc[2][2];
    acc[0][0] = zero16; acc[0][1] = zero16; acc[1][0] = zero16; acc[1][1] = zero16;

    auto mfma_phase = [&](int hc) {
        const char* ab = s_all + A_OFF(hc & 1);
        const char* bb = s_all + B_BASE;
        #pragma unroll
        for (int tap = 0; tap < 9; ++tap) {
            const int kh = tap / 3, kw = tap % 3;
            bf16x8 Bf0 = *(const bf16x8*)(bb + (size_t)((tap * 2 + hw) * 64 +      l31) * 16);
            bf16x8 Bf1 = *(const bf16x8*)(bb + (size_t)((tap * 2 + hw) * 64 + 32 + l31) * 16);
            bf16x8 Af0 = *(const bf16x8*)(ab + (wrow + kh) * 4224 + swz(wcb +      l31 + kw + 1, hw));
            bf16x8 Af1 = *(const bf16x8*)(ab + (wrow + kh) * 4224 + swz(wcb + 32 + l31 + kw + 1, hw));
            acc[0][0] = __builtin_amdgcn_mfma_f32_32x32x16_bf16(Af0, Bf0, acc[0][0], 0, 0, 0);
            acc[0][1] = __builtin_amdgcn_mfma_f32_32x32x16_bf16(Af0, Bf1, acc[0][1], 0, 0, 0);
            acc[1][0] = __builtin_amdgcn_mfma_f32_32x32x16_bf16(Af1, Bf0, acc[1][0], 0, 0, 0);
            acc[1][1] = __builtin_amdgcn_mfma_f32_32x32x16_bf16(Af1, Bf1, acc[1][1], 0, 0, 0);
        }
    };

    // ---- prologue: B(0) DMA'd, A(0) staged, A(1) left in flight ----
    issueB(0);
    issueA(0);
    writeA(0);                     // reg-deps drain A(0); in-order => B(0) too
    issueA(1);
    __builtin_amdgcn_sched_barrier(0);
    asm volatile("s_waitcnt vmcnt(9) lgkmcnt(0)" ::: "memory");  // A(1) in flight
    __builtin_amdgcn_s_barrier();
    __builtin_amdgcn_sched_barrier(0);

    // ---- main loop: 8 half-chunks of 16 cin, 2 barriers each ----
    #pragma unroll 1
    for (int h = 0; h < 8; ++h) {
        mfma_phase(h);
        __builtin_amdgcn_sched_barrier(0);
        __builtin_amdgcn_s_barrier();            // bar1: A(h),B(h) readers done
        __builtin_amdgcn_sched_barrier(0);
        if (h == 7) break;
        issueB(h + 1);                           // overwrite B (safe after bar1)
        writeA(h + 1);                           // into A-buf[(h+1)&1] (reads R)
        if (h < 6) issueA(h + 2);                // AFTER writeA: R reused safely
        if (h < 6) asm volatile("s_waitcnt vmcnt(9) lgkmcnt(0)" ::: "memory");
        else       asm volatile("s_waitcnt vmcnt(0) lgkmcnt(0)" ::: "memory");
        __builtin_amdgcn_s_barrier();            // bar2: A(h+1),B(h+1) ready
        __builtin_amdgcn_sched_barrier(0);
    }

    // ---- ReLU -> bf16 X tile in LDS (reuse A region @0), px-XOR swizzled ----
    __bf16* X = (__bf16*)s_all;                  // [256 px][64 ch] = 32 KB
    #pragma unroll
    for (int mt = 0; mt < 2; ++mt) {
        #pragma unroll
        for (int nt = 0; nt < 2; ++nt) {
            #pragma unroll
            for (int r = 0; r < 16; ++r) {
                float v = fmaxf(acc[mt][nt][r], 0.f);
                int mrow = (r & 3) + 8 * (r >> 2) + 4 * hw;
                int pxb  = wave * 64 + mt * 32 + mrow;
                int chn  = nt * 32 + l31;
                *(__bf16*)((char*)X + pxb * 128 + ((chn * 2) ^ ((pxb & 7) << 4))) = (__bf16)v;
            }
        }
    }

    // ---- stage 1x1-head weights + bias (post-loop, into dead B region) ----
    {
        char* s_wc = s_all + WC_BASE;
        float* s_bias = (float*)(s_all + BIAS_BASE);
        int och = tid >> 3;
        int j8  = (tid & 7) * 8;
        float v[8];
        if (och < 20) {
            const float* src = (och < 2)  ? (w_cls + och * 64)
                             : (och < 8)  ? (w_box + (och - 2) * 64)
                             : (och < 16) ? (w_dir + (och - 8) * 64)
                                          : (w_scr + (och - 16) * 64);
            #pragma unroll
            for (int j = 0; j < 8; ++j) v[j] = src[j8 + j];
        } else {
            #pragma unroll
            for (int j = 0; j < 8; ++j) v[j] = 0.f;
        }
        bf16x8 wv;
        #pragma unroll
        for (int j = 0; j < 8; ++j) wv[j] = (__bf16)v[j];
        *(bf16x8*)(s_wc + och * 128 + ((j8 * 2) ^ ((och & 7) << 4))) = wv;
        if (tid < 32) {
            s_bias[tid] = (tid < 2)  ? b_cls[tid]
                        : (tid < 8)  ? b_box[tid - 2]
                        : (tid < 16) ? b_dir[tid - 8]
                        : (tid < 20) ? b_scr[tid - 16] : 0.f;
        }
    }
    __syncthreads();   // wc/bias visible to all waves (X is wave-local)

    // ---- stage 2: out[och(20->32)][px] = Wc @ X, K=64 ----
    const char* s_wc = s_all + WC_BASE;
    const float* s_bias = (const float*)(s_all + BIAS_BASE);
    f32x16 acc2[2];
    acc2[0] = zero16; acc2[1] = zero16;
    #pragma unroll
    for (int ks = 0; ks < 4; ++ks) {
        int ch0 = ks * 16 + hw * 8;
        bf16x8 a2 = *(const bf16x8*)(s_wc + l31 * 128 + ((ch0 * 2) ^ ((l31 & 7) << 4)));
        #pragma unroll
        for (int nt = 0; nt < 2; ++nt) {
            int pxb = wave * 64 + nt * 32 + l31;
            bf16x8 b2 = *(const bf16x8*)((const char*)X + pxb * 128 + ((ch0 * 2) ^ ((pxb & 7) << 4)));
            acc2[nt] = __builtin_amdgcn_mfma_f32_32x32x16_bf16(a2, b2, acc2[nt], 0, 0, 0);
        }
    }

    // ---- epilogue: bias, sigmoid on och 16..19, coalesced stores ----
    const int h = h0 + wrow;
    #pragma unroll
    for (int nt = 0; nt < 2; ++nt) {
        int wg2 = w0 + wcb + nt * 32 + l31;
        #pragma unroll
        for (int r = 0; r < 16; ++r) {
            int och = (r & 3) + 8 * (r >> 2) + 4 * hw;
            if (och < 20) {
                float v = acc2[nt][r] + s_bias[och];
                if (och >= 16) v = 1.f / (1.f + __expf(-v));
                out[(((size_t)bz * 20 + och) * 512 + h) * 512 + wg2] = v;
            }
        }
    }
}

extern "C" void kernel_launch(void* const* d_in, const int* in_sizes, int n_in,
                              void* d_out, int out_size, void* d_ws, size_t ws_size,
                              hipStream_t stream) {
    const float* feature  = (const float*)d_in[0];
    const float* w_shared = (const float*)d_in[1];
    const float* w_cls = (const float*)d_in[2];
    const float* b_cls = (const float*)d_in[3];
    const float* w_box = (const float*)d_in[4];
    const float* b_box = (const float*)d_in[5];
    const float* w_dir = (const float*)d_in[6];
    const float* b_dir = (const float*)d_in[7];
    const float* w_scr = (const float*)d_in[8];
    const float* b_scr = (const float*)d_in[9];
    float* out = (float*)d_out;
    __bf16* ws3 = (__bf16*)d_ws;   // 8 * 18432 B = 147456 B

    prep_w_kernel<<<288, 256, 0, stream>>>(w_shared, ws3);

    det_main_kernel<<<4096, 256, 0, stream>>>(feature, ws3,
                                              w_cls, b_cls, w_box, b_box,
                                              w_dir, b_dir, w_scr, b_scr, out);
}

// Round 14
// 226.749 us; speedup vs baseline: 1.0076x; 1.0076x over previous
//
#include <hip/hip_runtime.h>
#include <cstdint>
#include <cstddef>

// ---------------------------------------------------------------------------
// DetCenterDense: fused conv3x3(128->64)+ReLU -> 4x conv1x1 heads (20 ch total,
// sigmoid on last 4) over [4,128,512,512] fp32, NCHW. bf16 MFMA implicit GEMM.
// R14: R13 (verified 228us) with writeA(h+1) moved out of the inter-barrier
//      window into the MFMA phase (target A-buf is free during phase h; its
//      input regs arrived last phase). sched_barrier between mfma_phase and
//      writeA removed so the compiler may interleave ds_writes with MFMAs.
//      Window now: issueB + issueA + vmcnt(9) only.
//   - ORDER MATTERS: writeA(h+1) (reads R) must precede issueA(h+2)
//     (overwrites R) — R12's WAR bug. Preserved here: writeA in phase,
//     issueA in the later window.
// Explored and rejected (measured): B-from-global (+28us), 4x64 tile (+33),
// 8-wave blocks (+17), mt=4 acc (spill), feat-transpose prepass (+118),
// setprio (neutral), issueA-before-writeA (WRONG).
// ---------------------------------------------------------------------------

typedef __bf16 bf16x8 __attribute__((ext_vector_type(8)));
typedef float f32x16 __attribute__((ext_vector_type(16)));
typedef float f32x4v __attribute__((ext_vector_type(4)));
typedef float f32x2v __attribute__((ext_vector_type(2)));

#define CHW (512 * 512)

// A-tile LDS swizzle (validated R3-R13): granule 16B at (slot s, octet o):
//   lin = s*32 + o*16 ; byte = lin ^ ((lin>>1)&0x10) ^ ((lin>>2)&0x60)
__device__ __forceinline__ int swz(int s, int o) {
    int lin = (s << 5) | (o << 4);
    return lin ^ ((lin >> 1) & 0x10) ^ ((lin >> 2) & 0x60);
}

// ---------------------------------------------------------------------------
// Prepass: repack w_shared [64][128][3][3] fp32 -> bf16, per-half-chunk
// contiguous: ws3 [hc(8)][tap(9)][hw(2)][och(64)][8 bf16]  (18432 B per hc)
// ---------------------------------------------------------------------------
__global__ void prep_w_kernel(const float* __restrict__ w, __bf16* __restrict__ ws3) {
    int idx = blockIdx.x * 256 + threadIdx.x;
    if (idx >= 64 * 128 * 9) return;
    int tap = idx % 9;
    int cin = (idx / 9) % 128;
    int och = idx / (9 * 128);
    int hc = cin >> 4;
    int hw = (cin >> 3) & 1;
    int j  = cin & 7;
    int dst = (((hc * 9 + tap) * 2 + hw) * 64 + och) * 8 + j;
    ws3[dst] = (__bf16)w[idx];
}

// LDS map (bytes), total 52224 -> 3 blocks/CU (156672 <= 163840):
//   A0 @ 0 [16896]   A1 @ 16896 [16896]   ([4 rows][132 slots x 32B], swz)
//   B  @ 33792 [18432] single buf: [tap 9][hw 2][och 64][8 bf16], linear.
//   After main loop: wc overlays @33792 [4096], bias @37888 [128]; X tile @0.
#define A_OFF(p)  ((p) ? 16896 : 0)
#define B_BASE    33792
#define WC_BASE   33792
#define BIAS_BASE 37888

__global__ __launch_bounds__(256, 3)
void det_main_kernel(const float* __restrict__ feature,
                     const __bf16* __restrict__ ws3,
                     const float* __restrict__ w_cls, const float* __restrict__ b_cls,
                     const float* __restrict__ w_box, const float* __restrict__ b_box,
                     const float* __restrict__ w_dir, const float* __restrict__ b_dir,
                     const float* __restrict__ w_scr, const float* __restrict__ b_scr,
                     float* __restrict__ out) {
    __shared__ __align__(1024) char s_all[52224];

    const int tid  = threadIdx.x;
    const int lane = tid & 63;
    const int wave = tid >> 6;
    const int l31  = lane & 31;
    const int hw   = lane >> 5;
    const int wrow = wave >> 1;
    const int wcb  = (wave & 1) * 64;

    // XCD-aware decode: 4096 blocks -> 8 chunks of 512; vertical neighbors
    // (sharing halo rows) schedule-adjacent within an XCD.
    const int bid = blockIdx.x;
    const int wg  = (bid & 7) * 512 + (bid >> 3);
    const int ck  = wg >> 9;
    const int bz  = ck >> 1;
    const int rem = wg & 511;
    const int h0  = (rem >> 1) * 2;
    const int w0  = ((ck & 1) * 2 + (rem & 1)) * 128;

    // ---- staging roles (R4-validated) ----
    // main: thread covers (cin octet m_hw, slot-quad m_q, row m_row): 8 dwordx4
    const int m_hw  = tid & 1;
    const int m_q   = (tid >> 1) & 31;
    const int m_row = tid >> 6;
    const int m_h   = h0 - 1 + m_row;
    const bool m_ok = (unsigned)m_h < 512u;
    const float* m_base = feature + (size_t)(bz * 128 + m_hw * 8) * CHW
                        + (size_t)(m_ok ? m_h : 0) * 512 + (w0 + 4 * m_q);
    // edge: even lanes of every wave (uniform per-wave instr count): 1 dwordx2
    const bool e_on = (tid & 1) == 0;
    const int e_idx = tid >> 1;
    const int e_ee  = (e_idx >> 6) & 1;
    const int e_row = (e_idx >> 4) & 3;
    const int e_cin = e_idx & 15;
    const int e_h   = h0 - 1 + e_row;
    const int e_w   = e_ee ? (w0 + 128) : (w0 - 2);
    const bool e_ok = ((unsigned)e_h < 512u) && ((unsigned)e_w < 511u);
    const float* e_base = feature + (size_t)(bz * 128 + e_cin) * CHW
                        + (size_t)(e_ok ? e_h : 0) * 512 + (e_ok ? e_w : 0);

    f32x4v R[8];      // 1-deep A prefetch (32 VGPR)
    f32x2v E;

    // issue A-loads for half-chunk hc: ALWAYS 9 vmem instrs per wave.
    auto issueA = [&](int hc) {
        const float* p = m_base + (size_t)(hc * 16) * CHW;
        #pragma unroll
        for (int j = 0; j < 8; ++j) R[j] = *(const f32x4v*)(p + (size_t)j * CHW);
        if (e_on) E = *(const f32x2v*)(e_base + (size_t)(hc * 16) * CHW);
    };

    // convert + ds_write into A-buf[hc&1]; zero OOB here (no vmem).
    auto writeA = [&](int hc) {
        char* ab = s_all + A_OFF(hc & 1);
        #pragma unroll
        for (int k = 0; k < 4; ++k) {
            bf16x8 g;
            #pragma unroll
            for (int j = 0; j < 8; ++j) g[j] = (__bf16)(m_ok ? R[j][k] : 0.f);
            *(bf16x8*)(ab + m_row * 4224 + swz(2 + 4 * m_q + k, m_hw)) = g;
        }
        if (e_on) {
            char* b2 = ab + e_row * 4224 + (e_cin & 7) * 2;
            int s0 = e_ee ? 130 : 0;
            *(__bf16*)(b2 + swz(s0,     e_cin >> 3)) = (__bf16)(e_ok ? E[0] : 0.f);
            *(__bf16*)(b2 + swz(s0 + 1, e_cin >> 3)) = (__bf16)(e_ok ? E[1] : 0.f);
        }
    };

    // async global->LDS of hc's weights into single B buffer (1152 x 16B).
    auto issueB = [&](int hc) {
        char* bb = s_all + B_BASE;
        const char* src = (const char*)ws3 + hc * 18432;
        #pragma unroll
        for (int i = 0; i < 4; ++i) {
            int g0 = i * 256 + wave * 64;
            __builtin_amdgcn_global_load_lds(
                (const __attribute__((address_space(1))) void*)(src + (size_t)(g0 + lane) * 16),
                (__attribute__((address_space(3))) void*)(bb + g0 * 16), 16, 0, 0);
        }
        if (wave < 2) {
            int g0 = 1024 + wave * 64;
            __builtin_amdgcn_global_load_lds(
                (const __attribute__((address_space(1))) void*)(src + (size_t)(g0 + lane) * 16),
                (__attribute__((address_space(3))) void*)(bb + g0 * 16), 16, 0, 0);
        }
    };

    f32x16 zero16;
    #pragma unroll
    for (int e = 0; e < 16; ++e) zero16[e] = 0.f;
    f32x16 acc[2][2];
    acc[0][0] = zero16; acc[0][1] = zero16; acc[1][0] = zero16; acc[1][1] = zero16;

    auto mfma_phase = [&](int hc) {
        const char* ab = s_all + A_OFF(hc & 1);
        const char* bb = s_all + B_BASE;
        #pragma unroll
        for (int tap = 0; tap < 9; ++tap) {
            const int kh = tap / 3, kw = tap % 3;
            bf16x8 Bf0 = *(const bf16x8*)(bb + (size_t)((tap * 2 + hw) * 64 +      l31) * 16);
            bf16x8 Bf1 = *(const bf16x8*)(bb + (size_t)((tap * 2 + hw) * 64 + 32 + l31) * 16);
            bf16x8 Af0 = *(const bf16x8*)(ab + (wrow + kh) * 4224 + swz(wcb +      l31 + kw + 1, hw));
            bf16x8 Af1 = *(const bf16x8*)(ab + (wrow + kh) * 4224 + swz(wcb + 32 + l31 + kw + 1, hw));
            acc[0][0] = __builtin_amdgcn_mfma_f32_32x32x16_bf16(Af0, Bf0, acc[0][0], 0, 0, 0);
            acc[0][1] = __builtin_amdgcn_mfma_f32_32x32x16_bf16(Af0, Bf1, acc[0][1], 0, 0, 0);
            acc[1][0] = __builtin_amdgcn_mfma_f32_32x32x16_bf16(Af1, Bf0, acc[1][0], 0, 0, 0);
            acc[1][1] = __builtin_amdgcn_mfma_f32_32x32x16_bf16(Af1, Bf1, acc[1][1], 0, 0, 0);
        }
    };

    // ---- prologue: B(0) DMA'd, A(0) staged, A(1) left in flight ----
    issueB(0);
    issueA(0);
    writeA(0);                     // reg-deps drain A(0); in-order => B(0) too
    issueA(1);
    __builtin_amdgcn_sched_barrier(0);
    asm volatile("s_waitcnt vmcnt(9) lgkmcnt(0)" ::: "memory");  // A(1) in flight
    __builtin_amdgcn_s_barrier();
    __builtin_amdgcn_sched_barrier(0);

    // ---- main loop: 8 half-chunks of 16 cin, 2 barriers each ----
    // writeA(h+1) lives INSIDE the phase (abuf[(h+1)&1] is free during phase
    // h; its readers finished at the previous bar1). No sched_barrier between
    // mfma_phase and writeA -> compiler may interleave ds_writes with MFMAs.
    #pragma unroll 1
    for (int h = 0; h < 8; ++h) {
        mfma_phase(h);
        if (h < 7) writeA(h + 1);                // in-phase; reads R (A(h+1))
        __builtin_amdgcn_sched_barrier(0);
        __builtin_amdgcn_s_barrier();            // bar1: A(h),B(h) readers done
        __builtin_amdgcn_sched_barrier(0);
        if (h == 7) break;
        issueB(h + 1);                           // overwrite B (safe after bar1)
        if (h < 6) issueA(h + 2);                // AFTER writeA (prev stmt): R free
        if (h < 6) asm volatile("s_waitcnt vmcnt(9) lgkmcnt(0)" ::: "memory");
        else       asm volatile("s_waitcnt vmcnt(0) lgkmcnt(0)" ::: "memory");
        __builtin_amdgcn_s_barrier();            // bar2: A(h+1),B(h+1) ready
        __builtin_amdgcn_sched_barrier(0);
    }

    // ---- ReLU -> bf16 X tile in LDS (reuse A region @0), px-XOR swizzled ----
    __bf16* X = (__bf16*)s_all;                  // [256 px][64 ch] = 32 KB
    #pragma unroll
    for (int mt = 0; mt < 2; ++mt) {
        #pragma unroll
        for (int nt = 0; nt < 2; ++nt) {
            #pragma unroll
            for (int r = 0; r < 16; ++r) {
                float v = fmaxf(acc[mt][nt][r], 0.f);
                int mrow = (r & 3) + 8 * (r >> 2) + 4 * hw;
                int pxb  = wave * 64 + mt * 32 + mrow;
                int chn  = nt * 32 + l31;
                *(__bf16*)((char*)X + pxb * 128 + ((chn * 2) ^ ((pxb & 7) << 4))) = (__bf16)v;
            }
        }
    }

    // ---- stage 1x1-head weights + bias (post-loop, into dead B region) ----
    {
        char* s_wc = s_all + WC_BASE;
        float* s_bias = (float*)(s_all + BIAS_BASE);
        int och = tid >> 3;
        int j8  = (tid & 7) * 8;
        float v[8];
        if (och < 20) {
            const float* src = (och < 2)  ? (w_cls + och * 64)
                             : (och < 8)  ? (w_box + (och - 2) * 64)
                             : (och < 16) ? (w_dir + (och - 8) * 64)
                                          : (w_scr + (och - 16) * 64);
            #pragma unroll
            for (int j = 0; j < 8; ++j) v[j] = src[j8 + j];
        } else {
            #pragma unroll
            for (int j = 0; j < 8; ++j) v[j] = 0.f;
        }
        bf16x8 wv;
        #pragma unroll
        for (int j = 0; j < 8; ++j) wv[j] = (__bf16)v[j];
        *(bf16x8*)(s_wc + och * 128 + ((j8 * 2) ^ ((och & 7) << 4))) = wv;
        if (tid < 32) {
            s_bias[tid] = (tid < 2)  ? b_cls[tid]
                        : (tid < 8)  ? b_box[tid - 2]
                        : (tid < 16) ? b_dir[tid - 8]
                        : (tid < 20) ? b_scr[tid - 16] : 0.f;
        }
    }
    __syncthreads();   // wc/bias visible to all waves (X is wave-local)

    // ---- stage 2: out[och(20->32)][px] = Wc @ X, K=64 ----
    const char* s_wc = s_all + WC_BASE;
    const float* s_bias = (const float*)(s_all + BIAS_BASE);
    f32x16 acc2[2];
    acc2[0] = zero16; acc2[1] = zero16;
    #pragma unroll
    for (int ks = 0; ks < 4; ++ks) {
        int ch0 = ks * 16 + hw * 8;
        bf16x8 a2 = *(const bf16x8*)(s_wc + l31 * 128 + ((ch0 * 2) ^ ((l31 & 7) << 4)));
        #pragma unroll
        for (int nt = 0; nt < 2; ++nt) {
            int pxb = wave * 64 + nt * 32 + l31;
            bf16x8 b2 = *(const bf16x8*)((const char*)X + pxb * 128 + ((ch0 * 2) ^ ((pxb & 7) << 4)));
            acc2[nt] = __builtin_amdgcn_mfma_f32_32x32x16_bf16(a2, b2, acc2[nt], 0, 0, 0);
        }
    }

    // ---- epilogue: bias, sigmoid on och 16..19, coalesced stores ----
    const int h = h0 + wrow;
    #pragma unroll
    for (int nt = 0; nt < 2; ++nt) {
        int wg2 = w0 + wcb + nt * 32 + l31;
        #pragma unroll
        for (int r = 0; r < 16; ++r) {
            int och = (r & 3) + 8 * (r >> 2) + 4 * hw;
            if (och < 20) {
                float v = acc2[nt][r] + s_bias[och];
                if (och >= 16) v = 1.f / (1.f + __expf(-v));
                out[(((size_t)bz * 20 + och) * 512 + h) * 512 + wg2] = v;
            }
        }
    }
}

extern "C" void kernel_launch(void* const* d_in, const int* in_sizes, int n_in,
                              void* d_out, int out_size, void* d_ws, size_t ws_size,
                              hipStream_t stream) {
    const float* feature  = (const float*)d_in[0];
    const float* w_shared = (const float*)d_in[1];
    const float* w_cls = (const float*)d_in[2];
    const float* b_cls = (const float*)d_in[3];
    const float* w_box = (const float*)d_in[4];
    const float* b_box = (const float*)d_in[5];
    const float* w_dir = (const float*)d_in[6];
    const float* b_dir = (const float*)d_in[7];
    const float* w_scr = (const float*)d_in[8];
    const float* b_scr = (const float*)d_in[9];
    float* out = (float*)d_out;
    __bf16* ws3 = (__bf16*)d_ws;   // 8 * 18432 B = 147456 B

    prep_w_kernel<<<288, 256, 0, stream>>>(w_shared, ws3);

    det_main_kernel<<<4096, 256, 0, stream>>>(feature, ws3,
                                              w_cls, b_cls, w_box, b_box,
                                              w_dir, b_dir, w_scr, b_scr, out);
}

// Round 15
// 224.135 us; speedup vs baseline: 1.0194x; 1.0117x over previous
//
#include <hip/hip_runtime.h>
#include <cstdint>
#include <cstddef>

// ---------------------------------------------------------------------------
// DetCenterDense: fused conv3x3(128->64)+ReLU -> 4x conv1x1 heads (20 ch total,
// sigmoid on last 4) over [4,128,512,512] fp32, NCHW. bf16 MFMA implicit GEMM.
// R15 (final): R14 (session best, 226.7us) + #pragma unroll 2 on the hc loop
//      so A-buffer parity (h&1) constant-folds per unrolled copy. All
//      barrier/vmcnt semantics textually identical per sub-iteration.
// Structure: 256-thr blocks, 12 waves/CU; A double-buffered LDS (swizzled) +
//      1-deep register prefetch; B single LDS buffer via global_load_lds;
//      2 barriers per 16-cin half-chunk; counted vmcnt(9) keeps A(h+2) in
//      flight across barriers; writeA(h+1) inside the MFMA phase (target buf
//      free, inputs arrived last phase); XCD-aware block swizzle; no setprio.
//   - ORDER MATTERS: writeA(h+1) (reads R) must precede issueA(h+2)
//     (overwrites R) — R12's WAR bug. Preserved: writeA in phase h,
//     issueA(h+2) in the later inter-barrier window.
// Explored and rejected (measured): B-from-global (+28us), 4x64 tile (+33),
// 8-wave blocks (+17), mt=4 acc (spill), feat-transpose prepass (+118),
// setprio (neutral), issueA-before-writeA (WRONG, absmax 9.5).
// ---------------------------------------------------------------------------

typedef __bf16 bf16x8 __attribute__((ext_vector_type(8)));
typedef float f32x16 __attribute__((ext_vector_type(16)));
typedef float f32x4v __attribute__((ext_vector_type(4)));
typedef float f32x2v __attribute__((ext_vector_type(2)));

#define CHW (512 * 512)

// A-tile LDS swizzle (validated R3-R14): granule 16B at (slot s, octet o):
//   lin = s*32 + o*16 ; byte = lin ^ ((lin>>1)&0x10) ^ ((lin>>2)&0x60)
__device__ __forceinline__ int swz(int s, int o) {
    int lin = (s << 5) | (o << 4);
    return lin ^ ((lin >> 1) & 0x10) ^ ((lin >> 2) & 0x60);
}

// ---------------------------------------------------------------------------
// Prepass: repack w_shared [64][128][3][3] fp32 -> bf16, per-half-chunk
// contiguous: ws3 [hc(8)][tap(9)][hw(2)][och(64)][8 bf16]  (18432 B per hc)
// ---------------------------------------------------------------------------
__global__ void prep_w_kernel(const float* __restrict__ w, __bf16* __restrict__ ws3) {
    int idx = blockIdx.x * 256 + threadIdx.x;
    if (idx >= 64 * 128 * 9) return;
    int tap = idx % 9;
    int cin = (idx / 9) % 128;
    int och = idx / (9 * 128);
    int hc = cin >> 4;
    int hw = (cin >> 3) & 1;
    int j  = cin & 7;
    int dst = (((hc * 9 + tap) * 2 + hw) * 64 + och) * 8 + j;
    ws3[dst] = (__bf16)w[idx];
}

// LDS map (bytes), total 52224 -> 3 blocks/CU (156672 <= 163840):
//   A0 @ 0 [16896]   A1 @ 16896 [16896]   ([4 rows][132 slots x 32B], swz)
//   B  @ 33792 [18432] single buf: [tap 9][hw 2][och 64][8 bf16], linear.
//   After main loop: wc overlays @33792 [4096], bias @37888 [128]; X tile @0.
#define A_OFF(p)  ((p) ? 16896 : 0)
#define B_BASE    33792
#define WC_BASE   33792
#define BIAS_BASE 37888

__global__ __launch_bounds__(256, 3)
void det_main_kernel(const float* __restrict__ feature,
                     const __bf16* __restrict__ ws3,
                     const float* __restrict__ w_cls, const float* __restrict__ b_cls,
                     const float* __restrict__ w_box, const float* __restrict__ b_box,
                     const float* __restrict__ w_dir, const float* __restrict__ b_dir,
                     const float* __restrict__ w_scr, const float* __restrict__ b_scr,
                     float* __restrict__ out) {
    __shared__ __align__(1024) char s_all[52224];

    const int tid  = threadIdx.x;
    const int lane = tid & 63;
    const int wave = tid >> 6;
    const int l31  = lane & 31;
    const int hw   = lane >> 5;
    const int wrow = wave >> 1;
    const int wcb  = (wave & 1) * 64;

    // XCD-aware decode: 4096 blocks -> 8 chunks of 512; vertical neighbors
    // (sharing halo rows) schedule-adjacent within an XCD.
    const int bid = blockIdx.x;
    const int wg  = (bid & 7) * 512 + (bid >> 3);
    const int ck  = wg >> 9;
    const int bz  = ck >> 1;
    const int rem = wg & 511;
    const int h0  = (rem >> 1) * 2;
    const int w0  = ((ck & 1) * 2 + (rem & 1)) * 128;

    // ---- staging roles (R4-validated) ----
    // main: thread covers (cin octet m_hw, slot-quad m_q, row m_row): 8 dwordx4
    const int m_hw  = tid & 1;
    const int m_q   = (tid >> 1) & 31;
    const int m_row = tid >> 6;
    const int m_h   = h0 - 1 + m_row;
    const bool m_ok = (unsigned)m_h < 512u;
    const float* m_base = feature + (size_t)(bz * 128 + m_hw * 8) * CHW
                        + (size_t)(m_ok ? m_h : 0) * 512 + (w0 + 4 * m_q);
    // edge: even lanes of every wave (uniform per-wave instr count): 1 dwordx2
    const bool e_on = (tid & 1) == 0;
    const int e_idx = tid >> 1;
    const int e_ee  = (e_idx >> 6) & 1;
    const int e_row = (e_idx >> 4) & 3;
    const int e_cin = e_idx & 15;
    const int e_h   = h0 - 1 + e_row;
    const int e_w   = e_ee ? (w0 + 128) : (w0 - 2);
    const bool e_ok = ((unsigned)e_h < 512u) && ((unsigned)e_w < 511u);
    const float* e_base = feature + (size_t)(bz * 128 + e_cin) * CHW
                        + (size_t)(e_ok ? e_h : 0) * 512 + (e_ok ? e_w : 0);

    f32x4v R[8];      // 1-deep A prefetch (32 VGPR)
    f32x2v E;

    // issue A-loads for half-chunk hc: ALWAYS 9 vmem instrs per wave.
    auto issueA = [&](int hc) {
        const float* p = m_base + (size_t)(hc * 16) * CHW;
        #pragma unroll
        for (int j = 0; j < 8; ++j) R[j] = *(const f32x4v*)(p + (size_t)j * CHW);
        if (e_on) E = *(const f32x2v*)(e_base + (size_t)(hc * 16) * CHW);
    };

    // convert + ds_write into A-buf[hc&1]; zero OOB here (no vmem).
    auto writeA = [&](int hc) {
        char* ab = s_all + A_OFF(hc & 1);
        #pragma unroll
        for (int k = 0; k < 4; ++k) {
            bf16x8 g;
            #pragma unroll
            for (int j = 0; j < 8; ++j) g[j] = (__bf16)(m_ok ? R[j][k] : 0.f);
            *(bf16x8*)(ab + m_row * 4224 + swz(2 + 4 * m_q + k, m_hw)) = g;
        }
        if (e_on) {
            char* b2 = ab + e_row * 4224 + (e_cin & 7) * 2;
            int s0 = e_ee ? 130 : 0;
            *(__bf16*)(b2 + swz(s0,     e_cin >> 3)) = (__bf16)(e_ok ? E[0] : 0.f);
            *(__bf16*)(b2 + swz(s0 + 1, e_cin >> 3)) = (__bf16)(e_ok ? E[1] : 0.f);
        }
    };

    // async global->LDS of hc's weights into single B buffer (1152 x 16B).
    auto issueB = [&](int hc) {
        char* bb = s_all + B_BASE;
        const char* src = (const char*)ws3 + hc * 18432;
        #pragma unroll
        for (int i = 0; i < 4; ++i) {
            int g0 = i * 256 + wave * 64;
            __builtin_amdgcn_global_load_lds(
                (const __attribute__((address_space(1))) void*)(src + (size_t)(g0 + lane) * 16),
                (__attribute__((address_space(3))) void*)(bb + g0 * 16), 16, 0, 0);
        }
        if (wave < 2) {
            int g0 = 1024 + wave * 64;
            __builtin_amdgcn_global_load_lds(
                (const __attribute__((address_space(1))) void*)(src + (size_t)(g0 + lane) * 16),
                (__attribute__((address_space(3))) void*)(bb + g0 * 16), 16, 0, 0);
        }
    };

    f32x16 zero16;
    #pragma unroll
    for (int e = 0; e < 16; ++e) zero16[e] = 0.f;
    f32x16 acc[2][2];
    acc[0][0] = zero16; acc[0][1] = zero16; acc[1][0] = zero16; acc[1][1] = zero16;

    auto mfma_phase = [&](int hc) {
        const char* ab = s_all + A_OFF(hc & 1);
        const char* bb = s_all + B_BASE;
        #pragma unroll
        for (int tap = 0; tap < 9; ++tap) {
            const int kh = tap / 3, kw = tap % 3;
            bf16x8 Bf0 = *(const bf16x8*)(bb + (size_t)((tap * 2 + hw) * 64 +      l31) * 16);
            bf16x8 Bf1 = *(const bf16x8*)(bb + (size_t)((tap * 2 + hw) * 64 + 32 + l31) * 16);
            bf16x8 Af0 = *(const bf16x8*)(ab + (wrow + kh) * 4224 + swz(wcb +      l31 + kw + 1, hw));
            bf16x8 Af1 = *(const bf16x8*)(ab + (wrow + kh) * 4224 + swz(wcb + 32 + l31 + kw + 1, hw));
            acc[0][0] = __builtin_amdgcn_mfma_f32_32x32x16_bf16(Af0, Bf0, acc[0][0], 0, 0, 0);
            acc[0][1] = __builtin_amdgcn_mfma_f32_32x32x16_bf16(Af0, Bf1, acc[0][1], 0, 0, 0);
            acc[1][0] = __builtin_amdgcn_mfma_f32_32x32x16_bf16(Af1, Bf0, acc[1][0], 0, 0, 0);
            acc[1][1] = __builtin_amdgcn_mfma_f32_32x32x16_bf16(Af1, Bf1, acc[1][1], 0, 0, 0);
        }
    };

    // ---- prologue: B(0) DMA'd, A(0) staged, A(1) left in flight ----
    issueB(0);
    issueA(0);
    writeA(0);                     // reg-deps drain A(0); in-order => B(0) too
    issueA(1);
    __builtin_amdgcn_sched_barrier(0);
    asm volatile("s_waitcnt vmcnt(9) lgkmcnt(0)" ::: "memory");  // A(1) in flight
    __builtin_amdgcn_s_barrier();
    __builtin_amdgcn_sched_barrier(0);

    // ---- main loop: 8 half-chunks of 16 cin, 2 barriers each ----
    // writeA(h+1) lives INSIDE the phase (abuf[(h+1)&1] is free during phase
    // h; its readers finished at the previous bar1). unroll 2 -> A_OFF(h&1)
    // constant-folds per copy; barrier/vmcnt sequence identical per sub-iter.
    #pragma unroll 2
    for (int h = 0; h < 8; ++h) {
        mfma_phase(h);
        if (h < 7) writeA(h + 1);                // in-phase; reads R (A(h+1))
        __builtin_amdgcn_sched_barrier(0);
        __builtin_amdgcn_s_barrier();            // bar1: A(h),B(h) readers done
        __builtin_amdgcn_sched_barrier(0);
        if (h == 7) break;
        issueB(h + 1);                           // overwrite B (safe after bar1)
        if (h < 6) issueA(h + 2);                // AFTER writeA (prev stmt): R free
        if (h < 6) asm volatile("s_waitcnt vmcnt(9) lgkmcnt(0)" ::: "memory");
        else       asm volatile("s_waitcnt vmcnt(0) lgkmcnt(0)" ::: "memory");
        __builtin_amdgcn_s_barrier();            // bar2: A(h+1),B(h+1) ready
        __builtin_amdgcn_sched_barrier(0);
    }

    // ---- ReLU -> bf16 X tile in LDS (reuse A region @0), px-XOR swizzled ----
    __bf16* X = (__bf16*)s_all;                  // [256 px][64 ch] = 32 KB
    #pragma unroll
    for (int mt = 0; mt < 2; ++mt) {
        #pragma unroll
        for (int nt = 0; nt < 2; ++nt) {
            #pragma unroll
            for (int r = 0; r < 16; ++r) {
                float v = fmaxf(acc[mt][nt][r], 0.f);
                int mrow = (r & 3) + 8 * (r >> 2) + 4 * hw;
                int pxb  = wave * 64 + mt * 32 + mrow;
                int chn  = nt * 32 + l31;
                *(__bf16*)((char*)X + pxb * 128 + ((chn * 2) ^ ((pxb & 7) << 4))) = (__bf16)v;
            }
        }
    }

    // ---- stage 1x1-head weights + bias (post-loop, into dead B region) ----
    {
        char* s_wc = s_all + WC_BASE;
        float* s_bias = (float*)(s_all + BIAS_BASE);
        int och = tid >> 3;
        int j8  = (tid & 7) * 8;
        float v[8];
        if (och < 20) {
            const float* src = (och < 2)  ? (w_cls + och * 64)
                             : (och < 8)  ? (w_box + (och - 2) * 64)
                             : (och < 16) ? (w_dir + (och - 8) * 64)
                                          : (w_scr + (och - 16) * 64);
            #pragma unroll
            for (int j = 0; j < 8; ++j) v[j] = src[j8 + j];
        } else {
            #pragma unroll
            for (int j = 0; j < 8; ++j) v[j] = 0.f;
        }
        bf16x8 wv;
        #pragma unroll
        for (int j = 0; j < 8; ++j) wv[j] = (__bf16)v[j];
        *(bf16x8*)(s_wc + och * 128 + ((j8 * 2) ^ ((och & 7) << 4))) = wv;
        if (tid < 32) {
            s_bias[tid] = (tid < 2)  ? b_cls[tid]
                        : (tid < 8)  ? b_box[tid - 2]
                        : (tid < 16) ? b_dir[tid - 8]
                        : (tid < 20) ? b_scr[tid - 16] : 0.f;
        }
    }
    __syncthreads();   // wc/bias visible to all waves (X is wave-local)

    // ---- stage 2: out[och(20->32)][px] = Wc @ X, K=64 ----
    const char* s_wc = s_all + WC_BASE;
    const float* s_bias = (const float*)(s_all + BIAS_BASE);
    f32x16 acc2[2];
    acc2[0] = zero16; acc2[1] = zero16;
    #pragma unroll
    for (int ks = 0; ks < 4; ++ks) {
        int ch0 = ks * 16 + hw * 8;
        bf16x8 a2 = *(const bf16x8*)(s_wc + l31 * 128 + ((ch0 * 2) ^ ((l31 & 7) << 4)));
        #pragma unroll
        for (int nt = 0; nt < 2; ++nt) {
            int pxb = wave * 64 + nt * 32 + l31;
            bf16x8 b2 = *(const bf16x8*)((const char*)X + pxb * 128 + ((ch0 * 2) ^ ((pxb & 7) << 4)));
            acc2[nt] = __builtin_amdgcn_mfma_f32_32x32x16_bf16(a2, b2, acc2[nt], 0, 0, 0);
        }
    }

    // ---- epilogue: bias, sigmoid on och 16..19, coalesced stores ----
    const int h = h0 + wrow;
    #pragma unroll
    for (int nt = 0; nt < 2; ++nt) {
        int wg2 = w0 + wcb + nt * 32 + l31;
        #pragma unroll
        for (int r = 0; r < 16; ++r) {
            int och = (r & 3) + 8 * (r >> 2) + 4 * hw;
            if (och < 20) {
                float v = acc2[nt][r] + s_bias[och];
                if (och >= 16) v = 1.f / (1.f + __expf(-v));
                out[(((size_t)bz * 20 + och) * 512 + h) * 512 + wg2] = v;
            }
        }
    }
}

extern "C" void kernel_launch(void* const* d_in, const int* in_sizes, int n_in,
                              void* d_out, int out_size, void* d_ws, size_t ws_size,
                              hipStream_t stream) {
    const float* feature  = (const float*)d_in[0];
    const float* w_shared = (const float*)d_in[1];
    const float* w_cls = (const float*)d_in[2];
    const float* b_cls = (const float*)d_in[3];
    const float* w_box = (const float*)d_in[4];
    const float* b_box = (const float*)d_in[5];
    const float* w_dir = (const float*)d_in[6];
    const float* b_dir = (const float*)d_in[7];
    const float* w_scr = (const float*)d_in[8];
    const float* b_scr = (const float*)d_in[9];
    float* out = (float*)d_out;
    __bf16* ws3 = (__bf16*)d_ws;   // 8 * 18432 B = 147456 B

    prep_w_kernel<<<288, 256, 0, stream>>>(w_shared, ws3);

    det_main_kernel<<<4096, 256, 0, stream>>>(feature, ws3,
                                              w_cls, b_cls, w_box, b_box,
                                              w_dir, b_dir, w_scr, b_scr, out);
}